// Round 2
// baseline (3893.980 us; speedup 1.0000x reference)
//
#include <hip/hip_runtime.h>

#define N_EMBD 1024
#define N_HEAD 16
#define HEADSZ 64
#define BATCH  2
#define SEQ    2048
#define ROWS   (BATCH*SEQ)   /* 4096 */

// ---------------------------------------------------------------------------
// Pack Wq/Wk/Wv [H][C][hs] -> w2 [C][3*C], col = which*1024 + h*64 + d
// ---------------------------------------------------------------------------
__global__ __launch_bounds__(256) void pack_w(const float* __restrict__ Wq,
                                              const float* __restrict__ Wk,
                                              const float* __restrict__ Wv,
                                              float* __restrict__ w2)
{
    int idx   = blockIdx.x * 256 + threadIdx.x;       // < 3*C*C = 3145728
    int which = idx >> 20;                            // C*C = 2^20
    int rem   = idx & ((1 << 20) - 1);
    int c     = rem >> 10;
    int col   = rem & 1023;
    int h     = col >> 6, d = col & 63;
    const float* src = (which == 0) ? Wq : (which == 1) ? Wk : Wv;
    w2[(size_t)c * 3072 + which * 1024 + col] =
        src[((size_t)h * N_EMBD + c) * HEADSZ + d];
}

// ---------------------------------------------------------------------------
// LayerNorm: one block per row of 1024, float4 loads
// ---------------------------------------------------------------------------
__global__ __launch_bounds__(256) void ln_k(const float* __restrict__ x,
                                            const float* __restrict__ g,
                                            const float* __restrict__ bta,
                                            float* __restrict__ out)
{
    const int row = blockIdx.x;
    const int tid = threadIdx.x;
    const float* xr = x + (size_t)row * N_EMBD;
    float4 v = *(const float4*)(xr + tid * 4);
    float s  = v.x + v.y + v.z + v.w;
    float s2 = v.x * v.x + v.y * v.y + v.z * v.z + v.w * v.w;
#pragma unroll
    for (int off = 32; off; off >>= 1) {
        s  += __shfl_xor(s,  off, 64);
        s2 += __shfl_xor(s2, off, 64);
    }
    __shared__ float rs[4], rs2[4];
    const int wave = tid >> 6, lane = tid & 63;
    if (lane == 0) { rs[wave] = s; rs2[wave] = s2; }
    __syncthreads();
    s  = rs[0] + rs[1] + rs[2] + rs[3];
    s2 = rs2[0] + rs2[1] + rs2[2] + rs2[3];
    const float mean = s * (1.f / N_EMBD);
    const float var  = s2 * (1.f / N_EMBD) - mean * mean;
    const float rsig = rsqrtf(var + 1e-5f);
    float4 gv = *(const float4*)(g + tid * 4);
    float4 bv = *(const float4*)(bta + tid * 4);
    float4 o;
    o.x = (v.x - mean) * rsig * gv.x + bv.x;
    o.y = (v.y - mean) * rsig * gv.y + bv.y;
    o.z = (v.z - mean) * rsig * gv.z + bv.z;
    o.w = (v.w - mean) * rsig * gv.w + bv.w;
    *(float4*)(out + (size_t)row * N_EMBD + tid * 4) = o;
}

// ---------------------------------------------------------------------------
// Tiled GEMM: C[M,N] = A[M,K] * B[K,N] (+bias)(relu?)(+resid), f32.
// BM=BN=64, BK=16, 256 threads, 4x4 microtile.
// M,N multiples of 64, K multiple of 16 (true at all call sites).
// ---------------------------------------------------------------------------
__global__ __launch_bounds__(256) void gemm_k(const float* __restrict__ A,
                                              const float* __restrict__ Bm,
                                              const float* __restrict__ bias,
                                              const float* __restrict__ resid,
                                              float* __restrict__ C,
                                              int M, int N, int K, int relu)
{
    __shared__ float As[16][68];   // [k][m]
    __shared__ float Bs[16][68];   // [k][n]
    const int tid = threadIdx.x;
    const int row0 = blockIdx.y * 64, col0 = blockIdx.x * 64;
    const int tx = tid & 15, ty = tid >> 4;
    const int am = tid >> 2,  ak = (tid & 3) * 4;   // A tile: 64 rows x 16 k
    const int bk = tid >> 4,  bn = (tid & 15) * 4;  // B tile: 16 k x 64 cols
    float acc[4][4] = {{0.f}};
    const float* aptr = A + (size_t)(row0 + am) * K + ak;
    const float* bptr = Bm + (size_t)bk * N + col0 + bn;

    for (int k0 = 0; k0 < K; k0 += 16) {
        float4 av = *(const float4*)aptr;
        float4 bv = *(const float4*)bptr;
        As[ak + 0][am] = av.x; As[ak + 1][am] = av.y;
        As[ak + 2][am] = av.z; As[ak + 3][am] = av.w;
        *(float4*)&Bs[bk][bn] = bv;   // row = 272 B, 16B-aligned
        __syncthreads();
#pragma unroll
        for (int kk = 0; kk < 16; ++kk) {
            float4 a4 = *(const float4*)&As[kk][ty * 4];
            float4 b4 = *(const float4*)&Bs[kk][tx * 4];
            float ar[4] = {a4.x, a4.y, a4.z, a4.w};
            float br[4] = {b4.x, b4.y, b4.z, b4.w};
#pragma unroll
            for (int i = 0; i < 4; ++i)
#pragma unroll
                for (int j = 0; j < 4; ++j)
                    acc[i][j] = fmaf(ar[i], br[j], acc[i][j]);
        }
        __syncthreads();
        aptr += 16;
        bptr += (size_t)16 * N;
    }

#pragma unroll
    for (int i = 0; i < 4; ++i) {
        const int r = row0 + ty * 4 + i;
#pragma unroll
        for (int j = 0; j < 4; ++j) {
            const int c = col0 + tx * 4 + j;
            float v = acc[i][j];
            if (bias)  v += bias[c];
            if (relu)  v = fmaxf(v, 0.f);
            if (resid) v += resid[(size_t)r * N + c];
            C[(size_t)r * N + c] = v;
        }
    }
}

// ---------------------------------------------------------------------------
// Causal multi-head attention, flash-style online softmax.
// qkv: [ROWS][3*C], q cols [0,1024), k cols [1024,2048), v cols [2048,3072)
// One wave per query row (hs=64=wave). Block = 4 waves = 4 consecutive rows.
// K/V tiles of 64 rows in LDS, pad 65 -> both compute loops 2 lanes/bank
// (free per m136).
// ---------------------------------------------------------------------------
__global__ __launch_bounds__(256) void attn_k(const float* __restrict__ qkv,
                                              float* __restrict__ att)
{
    __shared__ float Ks[64][65];
    __shared__ float Vs[64][65];
    const int tid  = threadIdx.x;
    const int wave = tid >> 6, lane = tid & 63;
    const int bh   = blockIdx.y;
    const int b    = bh >> 4, head = bh & 15;
    const int t0   = blockIdx.x * 4;
    const int t    = t0 + wave;
    const float scale = 0.125f;   // 64^-0.5

    const size_t rowbase = (size_t)(b * SEQ + t) * 3072;
    float q = qkv[rowbase + head * 64 + lane] * scale;

    float m = -INFINITY, l = 0.f, o = 0.f;
    const int ntiles = (t0 >> 6) + 1;   // all 4 rows share floor(t/64)

    const int sr = tid >> 2;          // 0..63 : row within K/V tile
    const int sc = (tid & 3) * 16;    // 0,16,32,48 : col base

    for (int j = 0; j < ntiles; ++j) {
        const int s0 = j * 64;
        __syncthreads();  // previous tile's LDS reads complete before overwrite
        {
            const size_t kb = (size_t)(b * SEQ + s0 + sr) * 3072
                              + N_EMBD + head * 64 + sc;
#pragma unroll
            for (int i = 0; i < 4; ++i) {
                float4 kv = *(const float4*)(qkv + kb + 4 * i);
                Ks[sr][sc + 4 * i + 0] = kv.x;
                Ks[sr][sc + 4 * i + 1] = kv.y;
                Ks[sr][sc + 4 * i + 2] = kv.z;
                Ks[sr][sc + 4 * i + 3] = kv.w;
                float4 vv = *(const float4*)(qkv + kb + N_EMBD + 4 * i);
                Vs[sr][sc + 4 * i + 0] = vv.x;
                Vs[sr][sc + 4 * i + 1] = vv.y;
                Vs[sr][sc + 4 * i + 2] = vv.z;
                Vs[sr][sc + 4 * i + 3] = vv.w;
            }
        }
        __syncthreads();

        // --- scores: lane = key index within tile ---
        float s = 0.f;
#pragma unroll
        for (int d = 0; d < 64; ++d) {
            float qd = __shfl(q, d, 64);
            s = fmaf(qd, Ks[lane][d], s);
        }
        if (s0 + lane > t) s = -INFINITY;

        float tm = s;
#pragma unroll
        for (int off = 32; off; off >>= 1) tm = fmaxf(tm, __shfl_xor(tm, off, 64));
        const float mnew  = fmaxf(m, tm);          // finite from tile 0 on
        const float p     = __expf(s - mnew);      // 0 for masked lanes
        const float alpha = __expf(m - mnew);      // 0 on first tile
        float ps = p;
#pragma unroll
        for (int off = 32; off; off >>= 1) ps += __shfl_xor(ps, off, 64);
        l = l * alpha + ps;
        o *= alpha;
        // --- PV: lane = output dim ---
#pragma unroll
        for (int ss = 0; ss < 64; ++ss) {
            float pv = __shfl(p, ss, 64);
            o = fmaf(pv, Vs[ss][lane], o);
        }
        m = mnew;
    }

    att[(size_t)(b * SEQ + t) * N_EMBD + head * 64 + lane] = o / l;
}

// ---------------------------------------------------------------------------
extern "C" void kernel_launch(void* const* d_in, const int* in_sizes, int n_in,
                              void* d_out, int out_size, void* d_ws, size_t ws_size,
                              hipStream_t stream)
{
    const float* x     = (const float*)d_in[0];
    const float* Wq    = (const float*)d_in[1];
    const float* Wk    = (const float*)d_in[2];
    const float* Wv    = (const float*)d_in[3];
    const float* Wproj = (const float*)d_in[4];
    const float* bproj = (const float*)d_in[5];
    const float* g1    = (const float*)d_in[6];
    const float* b1    = (const float*)d_in[7];
    const float* g2    = (const float*)d_in[8];
    const float* b2    = (const float*)d_in[9];
    const float* Wff1  = (const float*)d_in[10];
    const float* bff1  = (const float*)d_in[11];
    const float* Wff2  = (const float*)d_in[12];
    const float* bff2  = (const float*)d_in[13];
    float* out = (float*)d_out;

    char* ws = (char*)d_ws;
    // workspace layout (f32), with aliasing (113.25 MB total):
    //   w2   [1024,3072]            @ 0           (12.58 MB)
    //   h    [4096,1024] (=h2)      @ 12582912    (16.78 MB)
    //   qkv  [4096,3072]            @ 29360128    (50.33 MB)  \ ff [4096,4096]
    //   att  [4096,1024]            @ 79691776    (16.78 MB)  / aliases both
    //   x2   [4096,1024]            @ 96468992    (16.78 MB)
    float* w2  = (float*)(ws + 0);
    float* h   = (float*)(ws + 12582912);
    float* qkv = (float*)(ws + 29360128);
    float* att = (float*)(ws + 79691776);
    float* x2  = (float*)(ws + 96468992);
    float* h2  = h;     // h dead after QKV GEMM
    float* ff  = qkv;   // qkv dead after attention; att dead after proj GEMM

    pack_w<<<12288, 256, 0, stream>>>(Wq, Wk, Wv, w2);
    ln_k<<<ROWS, 256, 0, stream>>>(x, g1, b1, h);
    // QKV: [4096,1024] x [1024,3072]
    gemm_k<<<dim3(3072 / 64, ROWS / 64), 256, 0, stream>>>(
        h, w2, nullptr, nullptr, qkv, ROWS, 3072, N_EMBD, 0);
    attn_k<<<dim3(SEQ / 4, BATCH * N_HEAD), 256, 0, stream>>>(qkv, att);
    // proj + bias + residual(x) -> x2
    gemm_k<<<dim3(N_EMBD / 64, ROWS / 64), 256, 0, stream>>>(
        att, Wproj, bproj, x, x2, ROWS, N_EMBD, N_EMBD, 0);
    ln_k<<<ROWS, 256, 0, stream>>>(x2, g2, b2, h2);
    // FF1 + bias + relu
    gemm_k<<<dim3(4096 / 64, ROWS / 64), 256, 0, stream>>>(
        h2, Wff1, bff1, nullptr, ff, ROWS, 4096, N_EMBD, 1);
    // FF2 + bias + residual(x2) -> out
    gemm_k<<<dim3(N_EMBD / 64, ROWS / 64), 256, 0, stream>>>(
        ff, Wff2, bff2, x2, out, ROWS, N_EMBD, 4096, 0);
}

// Round 3
// 1903.877 us; speedup vs baseline: 2.0453x; 2.0453x over previous
//
#include <hip/hip_runtime.h>

#define N_EMBD 1024
#define N_HEAD 16
#define HEADSZ 64
#define BATCH  2
#define SEQ    2048
#define ROWS   (BATCH*SEQ)   /* 4096 */

// ---------------------------------------------------------------------------
// Pack Wq/Wk/Wv [H][C][hs] -> w2 [C][3*C], col = which*1024 + h*64 + d
// ---------------------------------------------------------------------------
__global__ __launch_bounds__(256) void pack_w(const float* __restrict__ Wq,
                                              const float* __restrict__ Wk,
                                              const float* __restrict__ Wv,
                                              float* __restrict__ w2)
{
    int idx   = blockIdx.x * 256 + threadIdx.x;       // < 3*C*C = 3145728
    int which = idx >> 20;                            // C*C = 2^20
    int rem   = idx & ((1 << 20) - 1);
    int c     = rem >> 10;
    int col   = rem & 1023;
    int h     = col >> 6, d = col & 63;
    const float* src = (which == 0) ? Wq : (which == 1) ? Wk : Wv;
    w2[(size_t)c * 3072 + which * 1024 + col] =
        src[((size_t)h * N_EMBD + c) * HEADSZ + d];
}

// ---------------------------------------------------------------------------
// LayerNorm: one block per row of 1024, float4 loads
// ---------------------------------------------------------------------------
__global__ __launch_bounds__(256) void ln_k(const float* __restrict__ x,
                                            const float* __restrict__ g,
                                            const float* __restrict__ bta,
                                            float* __restrict__ out)
{
    const int row = blockIdx.x;
    const int tid = threadIdx.x;
    const float* xr = x + (size_t)row * N_EMBD;
    float4 v = *(const float4*)(xr + tid * 4);
    float s  = v.x + v.y + v.z + v.w;
    float s2 = v.x * v.x + v.y * v.y + v.z * v.z + v.w * v.w;
#pragma unroll
    for (int off = 32; off; off >>= 1) {
        s  += __shfl_xor(s,  off, 64);
        s2 += __shfl_xor(s2, off, 64);
    }
    __shared__ float rs[4], rs2[4];
    const int wave = tid >> 6, lane = tid & 63;
    if (lane == 0) { rs[wave] = s; rs2[wave] = s2; }
    __syncthreads();
    s  = rs[0] + rs[1] + rs[2] + rs[3];
    s2 = rs2[0] + rs2[1] + rs2[2] + rs2[3];
    const float mean = s * (1.f / N_EMBD);
    const float var  = s2 * (1.f / N_EMBD) - mean * mean;
    const float rsig = rsqrtf(var + 1e-5f);
    float4 gv = *(const float4*)(g + tid * 4);
    float4 bv = *(const float4*)(bta + tid * 4);
    float4 o;
    o.x = (v.x - mean) * rsig * gv.x + bv.x;
    o.y = (v.y - mean) * rsig * gv.y + bv.y;
    o.z = (v.z - mean) * rsig * gv.z + bv.z;
    o.w = (v.w - mean) * rsig * gv.w + bv.w;
    *(float4*)(out + (size_t)row * N_EMBD + tid * 4) = o;
}

// ---------------------------------------------------------------------------
// Tiled GEMM: C[M,N] = A[M,K] * B[K,N] (+bias)(relu?)(+resid), f32.
// BM=BN=64, BK=16, 256 threads, 4x4 microtile.
// ---------------------------------------------------------------------------
__global__ __launch_bounds__(256) void gemm_k(const float* __restrict__ A,
                                              const float* __restrict__ Bm,
                                              const float* __restrict__ bias,
                                              const float* __restrict__ resid,
                                              float* __restrict__ C,
                                              int M, int N, int K, int relu)
{
    __shared__ float As[16][68];   // [k][m]
    __shared__ float Bs[16][68];   // [k][n]
    const int tid = threadIdx.x;
    const int row0 = blockIdx.y * 64, col0 = blockIdx.x * 64;
    const int tx = tid & 15, ty = tid >> 4;
    const int am = tid >> 2,  ak = (tid & 3) * 4;
    const int bk = tid >> 4,  bn = (tid & 15) * 4;
    float acc[4][4] = {{0.f}};
    const float* aptr = A + (size_t)(row0 + am) * K + ak;
    const float* bptr = Bm + (size_t)bk * N + col0 + bn;

    for (int k0 = 0; k0 < K; k0 += 16) {
        float4 av = *(const float4*)aptr;
        float4 bv = *(const float4*)bptr;
        As[ak + 0][am] = av.x; As[ak + 1][am] = av.y;
        As[ak + 2][am] = av.z; As[ak + 3][am] = av.w;
        *(float4*)&Bs[bk][bn] = bv;
        __syncthreads();
#pragma unroll
        for (int kk = 0; kk < 16; ++kk) {
            float4 a4 = *(const float4*)&As[kk][ty * 4];
            float4 b4 = *(const float4*)&Bs[kk][tx * 4];
            float ar[4] = {a4.x, a4.y, a4.z, a4.w};
            float br[4] = {b4.x, b4.y, b4.z, b4.w};
#pragma unroll
            for (int i = 0; i < 4; ++i)
#pragma unroll
                for (int j = 0; j < 4; ++j)
                    acc[i][j] = fmaf(ar[i], br[j], acc[i][j]);
        }
        __syncthreads();
        aptr += 16;
        bptr += (size_t)16 * N;
    }

#pragma unroll
    for (int i = 0; i < 4; ++i) {
        const int r = row0 + ty * 4 + i;
#pragma unroll
        for (int j = 0; j < 4; ++j) {
            const int c = col0 + tx * 4 + j;
            float v = acc[i][j];
            if (bias)  v += bias[c];
            if (relu)  v = fmaxf(v, 0.f);
            if (resid) v += resid[(size_t)r * N + c];
            C[(size_t)r * N + c] = v;
        }
    }
}

// ---------------------------------------------------------------------------
// Flash-tile causal attention. Block = 256 threads owns a 64-query tile of
// one (b,head); processes the q-tile PAIR {bx, 31-bx} for load balance
// (uniform 33 key-tiles per block). Per key-tile:
//   S = Q·K^T as a 64x64x64 GEMM (4x4 microtile/thread, float4 LDS reads),
//   online softmax (16-lane shuffle row-reduce),
//   P staged in LDS (aliases dead K tile), O += P·V as a second GEMM.
// LDS: Qs+KP+Vs = 49.9 KB -> 3 blocks/CU.
// ---------------------------------------------------------------------------
__global__ __launch_bounds__(256) void attn_k(const float* __restrict__ qkv,
                                              float* __restrict__ att)
{
    __shared__ float Qs[64][65];   // [d][i]  (transposed)
    __shared__ float KP[64][65];   // K tile [d][s] -> reused as P tile [s][i]
    __shared__ float Vs[64][65];   // [s][d]
    const int tid  = threadIdx.x;
    const int tx   = tid & 15, ty = tid >> 4;
    const int bh   = blockIdx.y;
    const int b    = bh >> 4, head = bh & 15;
    const int sr   = tid >> 2;          // 0..63 : row for staging
    const int sc   = (tid & 3) * 16;    // 0,16,32,48 : col base for staging
    const float scale = 0.125f;         // 64^-0.5

#pragma unroll
    for (int pass = 0; pass < 2; ++pass) {
        const int qt = pass == 0 ? blockIdx.x : 31 - blockIdx.x;
        const int t0 = qt * 64;

        // stage Q transposed (scaled). Safe: all LDS reads of the previous
        // pass (KP/Vs in PV) don't touch Qs, and the first in-loop barrier
        // orders these writes before any read.
        {
            const size_t qb = (size_t)(b * SEQ + t0 + sr) * 3072 + head * 64 + sc;
#pragma unroll
            for (int i = 0; i < 16; i += 4) {
                float4 qv = *(const float4*)(qkv + qb + i);
                Qs[sc + i + 0][sr] = qv.x * scale;
                Qs[sc + i + 1][sr] = qv.y * scale;
                Qs[sc + i + 2][sr] = qv.z * scale;
                Qs[sc + i + 3][sr] = qv.w * scale;
            }
        }

        float m[4], l[4], O[4][4];
#pragma unroll
        for (int i = 0; i < 4; ++i) {
            m[i] = -INFINITY; l[i] = 0.f;
#pragma unroll
            for (int j = 0; j < 4; ++j) O[i][j] = 0.f;
        }

        const int ntiles = qt + 1;
        for (int kt = 0; kt < ntiles; ++kt) {
            const int s0 = kt * 64;
            __syncthreads();   // prev PV reads of KP/Vs done; Qs writes ordered
            // stage K transposed [d][s], V direct [s][d]
            {
                const size_t kb = (size_t)(b * SEQ + s0 + sr) * 3072
                                  + N_EMBD + head * 64 + sc;
#pragma unroll
                for (int i = 0; i < 16; i += 4) {
                    float4 kv = *(const float4*)(qkv + kb + i);
                    KP[sc + i + 0][sr] = kv.x;
                    KP[sc + i + 1][sr] = kv.y;
                    KP[sc + i + 2][sr] = kv.z;
                    KP[sc + i + 3][sr] = kv.w;
                    *(float4*)&Vs[sr][sc + i] = *(const float4*)(qkv + kb + N_EMBD + i);
                }
            }
            __syncthreads();

            // --- S = Q.K^T : 64x64x64, 4x4 per thread ---
            float S[4][4] = {{0.f}};
#pragma unroll 8
            for (int kk = 0; kk < 64; ++kk) {
                float4 a4 = *(const float4*)&Qs[kk][ty * 4];
                float4 b4 = *(const float4*)&KP[kk][tx * 4];
                float ar[4] = {a4.x, a4.y, a4.z, a4.w};
                float br[4] = {b4.x, b4.y, b4.z, b4.w};
#pragma unroll
                for (int i = 0; i < 4; ++i)
#pragma unroll
                    for (int j = 0; j < 4; ++j)
                        S[i][j] = fmaf(ar[i], br[j], S[i][j]);
            }
            if (s0 == t0) {   // diagonal tile: causal mask
#pragma unroll
                for (int i = 0; i < 4; ++i)
#pragma unroll
                    for (int j = 0; j < 4; ++j)
                        if (tx * 4 + j > ty * 4 + i) S[i][j] = -INFINITY;
            }

            // --- online softmax (rows owned by 16-lane groups: same ty) ---
#pragma unroll
            for (int i = 0; i < 4; ++i) {
                float rm = fmaxf(fmaxf(S[i][0], S[i][1]), fmaxf(S[i][2], S[i][3]));
#pragma unroll
                for (int off = 8; off; off >>= 1) rm = fmaxf(rm, __shfl_xor(rm, off, 64));
                const float mn    = fmaxf(m[i], rm);
                const float alpha = __expf(m[i] - mn);   // 0 on first tile
                float ps = 0.f;
#pragma unroll
                for (int j = 0; j < 4; ++j) {
                    S[i][j] = __expf(S[i][j] - mn);      // 0 for masked
                    ps += S[i][j];
                }
#pragma unroll
                for (int off = 8; off; off >>= 1) ps += __shfl_xor(ps, off, 64);
                l[i] = l[i] * alpha + ps;
#pragma unroll
                for (int j = 0; j < 4; ++j) O[i][j] *= alpha;
                m[i] = mn;
            }

            __syncthreads();   // all S reads of KP done before P overwrite
#pragma unroll
            for (int i = 0; i < 4; ++i)
#pragma unroll
                for (int j = 0; j < 4; ++j)
                    KP[tx * 4 + j][ty * 4 + i] = S[i][j];   // P as [s][i]
            __syncthreads();

            // --- O += P.V : 64x64x64 ---
#pragma unroll 8
            for (int kk = 0; kk < 64; ++kk) {
                float4 p4 = *(const float4*)&KP[kk][ty * 4];
                float4 v4 = *(const float4*)&Vs[kk][tx * 4];
                float pr[4] = {p4.x, p4.y, p4.z, p4.w};
                float vr[4] = {v4.x, v4.y, v4.z, v4.w};
#pragma unroll
                for (int i = 0; i < 4; ++i)
#pragma unroll
                    for (int j = 0; j < 4; ++j)
                        O[i][j] = fmaf(pr[i], vr[j], O[i][j]);
            }
        }

        // write: rows t0+ty*4+i, cols head*64+tx*4..+3
#pragma unroll
        for (int i = 0; i < 4; ++i) {
            const float inv = 1.f / l[i];
            float4 o4 = make_float4(O[i][0] * inv, O[i][1] * inv,
                                    O[i][2] * inv, O[i][3] * inv);
            *(float4*)(att + (size_t)(b * SEQ + t0 + ty * 4 + i) * N_EMBD
                       + head * 64 + tx * 4) = o4;
        }
        __syncthreads();   // pass isolation before Qs restage
    }
}

// ---------------------------------------------------------------------------
extern "C" void kernel_launch(void* const* d_in, const int* in_sizes, int n_in,
                              void* d_out, int out_size, void* d_ws, size_t ws_size,
                              hipStream_t stream)
{
    const float* x     = (const float*)d_in[0];
    const float* Wq    = (const float*)d_in[1];
    const float* Wk    = (const float*)d_in[2];
    const float* Wv    = (const float*)d_in[3];
    const float* Wproj = (const float*)d_in[4];
    const float* bproj = (const float*)d_in[5];
    const float* g1    = (const float*)d_in[6];
    const float* b1    = (const float*)d_in[7];
    const float* g2    = (const float*)d_in[8];
    const float* b2    = (const float*)d_in[9];
    const float* Wff1  = (const float*)d_in[10];
    const float* bff1  = (const float*)d_in[11];
    const float* Wff2  = (const float*)d_in[12];
    const float* bff2  = (const float*)d_in[13];
    float* out = (float*)d_out;

    char* ws = (char*)d_ws;
    // workspace layout (f32), with aliasing (113.25 MB total):
    float* w2  = (float*)(ws + 0);           // [1024,3072]
    float* h   = (float*)(ws + 12582912);    // [4096,1024] (=h2)
    float* qkv = (float*)(ws + 29360128);    // [4096,3072] (ff aliases)
    float* att = (float*)(ws + 79691776);    // [4096,1024]
    float* x2  = (float*)(ws + 96468992);    // [4096,1024]
    float* h2  = h;
    float* ff  = qkv;

    pack_w<<<12288, 256, 0, stream>>>(Wq, Wk, Wv, w2);
    ln_k<<<ROWS, 256, 0, stream>>>(x, g1, b1, h);
    gemm_k<<<dim3(3072 / 64, ROWS / 64), 256, 0, stream>>>(
        h, w2, nullptr, nullptr, qkv, ROWS, 3072, N_EMBD, 0);
    attn_k<<<dim3(SEQ / 128, BATCH * N_HEAD), 256, 0, stream>>>(qkv, att);
    gemm_k<<<dim3(N_EMBD / 64, ROWS / 64), 256, 0, stream>>>(
        att, Wproj, bproj, x, x2, ROWS, N_EMBD, N_EMBD, 0);
    ln_k<<<ROWS, 256, 0, stream>>>(x2, g2, b2, h2);
    gemm_k<<<dim3(4096 / 64, ROWS / 64), 256, 0, stream>>>(
        h2, Wff1, bff1, nullptr, ff, ROWS, 4096, N_EMBD, 1);
    gemm_k<<<dim3(N_EMBD / 64, ROWS / 64), 256, 0, stream>>>(
        ff, Wff2, bff2, x2, out, ROWS, N_EMBD, 4096, 0);
}

// Round 4
// 787.192 us; speedup vs baseline: 4.9467x; 2.4186x over previous
//
#include <hip/hip_runtime.h>
#include <hip/hip_bf16.h>

#define N_EMBD 1024
#define N_HEAD 16
#define HEADSZ 64
#define BATCH  2
#define SEQ    2048
#define ROWS   (BATCH*SEQ)   /* 4096 */

typedef __attribute__((ext_vector_type(8))) short bf16x8;
typedef __attribute__((ext_vector_type(4))) float f32x4;

__device__ __forceinline__ short f2bs(float v){
    union { __hip_bfloat16 b; short s; } u; u.b = __float2bfloat16(v); return u.s;
}
__device__ __forceinline__ void gload16(const short* g, short* l){
    __builtin_amdgcn_global_load_lds(
        (const __attribute__((address_space(1))) unsigned int*)g,
        (__attribute__((address_space(3))) unsigned int*)l, 16, 0, 0);
}

// ---------------------------------------------------------------------------
// Transpose + f32->bf16 convert: out[j][i] = in[i][j]; in is [R][Cc] f32.
// Block 256 = 32x8 threads, 32x32 LDS tile. R, Cc multiples of 32.
// z-dim for batched sub-matrices (QKV heads).
// ---------------------------------------------------------------------------
__global__ __launch_bounds__(256) void tr_cvt(const float* __restrict__ in,
                                              short* __restrict__ out,
                                              int R, int Cc,
                                              size_t in_z, size_t out_z)
{
    __shared__ float t[32][33];
    const int tx = threadIdx.x & 31, ty = threadIdx.x >> 5;
    const int j0 = blockIdx.x * 32, i0 = blockIdx.y * 32;
    const float* ip = in + (size_t)blockIdx.z * in_z;
    short* op = out + (size_t)blockIdx.z * out_z;
#pragma unroll
    for (int p = 0; p < 4; ++p)
        t[ty + p * 8][tx] = ip[(size_t)(i0 + ty + p * 8) * Cc + j0 + tx];
    __syncthreads();
#pragma unroll
    for (int p = 0; p < 4; ++p)
        op[(size_t)(j0 + ty + p * 8) * R + i0 + tx] = f2bs(t[tx][ty + p * 8]);
}

// ---------------------------------------------------------------------------
// LayerNorm: one block per row of 1024, float4 loads, bf16 output
// ---------------------------------------------------------------------------
__global__ __launch_bounds__(256) void ln_k(const float* __restrict__ x,
                                            const float* __restrict__ g,
                                            const float* __restrict__ bta,
                                            short* __restrict__ out)
{
    const int row = blockIdx.x;
    const int tid = threadIdx.x;
    const float* xr = x + (size_t)row * N_EMBD;
    float4 v = *(const float4*)(xr + tid * 4);
    float s  = v.x + v.y + v.z + v.w;
    float s2 = v.x * v.x + v.y * v.y + v.z * v.z + v.w * v.w;
#pragma unroll
    for (int off = 32; off; off >>= 1) {
        s  += __shfl_xor(s,  off, 64);
        s2 += __shfl_xor(s2, off, 64);
    }
    __shared__ float rs[4], rs2[4];
    const int wave = tid >> 6, lane = tid & 63;
    if (lane == 0) { rs[wave] = s; rs2[wave] = s2; }
    __syncthreads();
    s  = rs[0] + rs[1] + rs[2] + rs[3];
    s2 = rs2[0] + rs2[1] + rs2[2] + rs2[3];
    const float mean = s * (1.f / N_EMBD);
    const float var  = s2 * (1.f / N_EMBD) - mean * mean;
    const float rsig = rsqrtf(var + 1e-5f);
    float4 gv = *(const float4*)(g + tid * 4);
    float4 bv = *(const float4*)(bta + tid * 4);
    short4 o;
    o.x = f2bs((v.x - mean) * rsig * gv.x + bv.x);
    o.y = f2bs((v.y - mean) * rsig * gv.y + bv.y);
    o.z = f2bs((v.z - mean) * rsig * gv.z + bv.z);
    o.w = f2bs((v.w - mean) * rsig * gv.w + bv.w);
    *(short4*)(out + (size_t)row * N_EMBD + tid * 4) = o;
}

// ---------------------------------------------------------------------------
// MFMA GEMM (m97 structure): C[M,N] = A[M,K] * Bt[N,K]^T, bf16 in, f32 acc.
// 128x128 tile, BK=32, 256 threads = 4 waves, each wave 64x64 (4x4 MFMAs of
// 16x16x32). Staging via global_load_lds width=16 (LDS dest = wave base +
// lane*16 -> unpadded row-major tiles). Epilogue: +bias, relu?, +resid(f32),
// out -> f32 or bf16.
// ---------------------------------------------------------------------------
__global__ __launch_bounds__(256) void mfma_gemm(
    const short* __restrict__ A,    // [M][K] bf16
    const short* __restrict__ Bt,   // [N][K] bf16
    const float* __restrict__ bias,
    const float* __restrict__ resid,
    float* __restrict__ outf,
    short* __restrict__ outb,
    int M, int N, int K, int relu)
{
    __shared__ __align__(16) short As[128 * 32];
    __shared__ __align__(16) short Bs[128 * 32];
    const int tid  = threadIdx.x;
    const int lane = tid & 63, w = tid >> 6;
    const int quad = lane >> 4, l16 = lane & 15;
    const int row0 = blockIdx.y * 128, col0 = blockIdx.x * 128;
    const int wm = (w >> 1) * 64, wn = (w & 1) * 64;

    f32x4 acc[4][4];
#pragma unroll
    for (int i = 0; i < 4; ++i)
#pragma unroll
        for (int j = 0; j < 4; ++j)
            acc[i][j] = f32x4{0.f, 0.f, 0.f, 0.f};

    // staging: chunk = 16B = 8 bf16; A tile [128][32] = 512 chunks; wave w
    // owns chunks [w*128, w*128+128): two wave-instrs (t=0,1), lane -> chunk.
    const int c0  = w * 128 + lane;
    const int c1  = c0 + 64;
    const int ar0 = c0 >> 2, ak0 = (c0 & 3) * 8;
    const int ar1 = c1 >> 2, ak1 = (c1 & 3) * 8;
    const short* aG0 = A  + (size_t)(row0 + ar0) * K + ak0;
    const short* aG1 = A  + (size_t)(row0 + ar1) * K + ak1;
    const short* bG0 = Bt + (size_t)(col0 + ar0) * K + ak0;
    const short* bG1 = Bt + (size_t)(col0 + ar1) * K + ak1;
    short* aL0 = As + (size_t)w * 1024;        // (w*128)*8 shorts
    short* aL1 = aL0 + 512;
    short* bL0 = Bs + (size_t)w * 1024;
    short* bL1 = bL0 + 512;

    for (int k0 = 0; k0 < K; k0 += 32) {
        __syncthreads();
        gload16(aG0 + k0, aL0);
        gload16(aG1 + k0, aL1);
        gload16(bG0 + k0, bL0);
        gload16(bG1 + k0, bL1);
        asm volatile("s_waitcnt vmcnt(0)" ::: "memory");
        __syncthreads();

        bf16x8 af[4], bfr[4];
#pragma unroll
        for (int i = 0; i < 4; ++i)
            af[i]  = *(const bf16x8*)(As + (wm + i * 16 + l16) * 32 + quad * 8);
#pragma unroll
        for (int j = 0; j < 4; ++j)
            bfr[j] = *(const bf16x8*)(Bs + (wn + j * 16 + l16) * 32 + quad * 8);
#pragma unroll
        for (int i = 0; i < 4; ++i)
#pragma unroll
            for (int j = 0; j < 4; ++j)
                acc[i][j] = __builtin_amdgcn_mfma_f32_16x16x32_bf16(
                    af[i], bfr[j], acc[i][j], 0, 0, 0);
    }

    // epilogue: C/D layout row=quad*4+reg, col=lane&15 (m89/m91)
#pragma unroll
    for (int i = 0; i < 4; ++i) {
        const int rbase = row0 + wm + i * 16 + quad * 4;
#pragma unroll
        for (int j = 0; j < 4; ++j) {
            const int c = col0 + wn + j * 16 + l16;
            const float bv = bias ? bias[c] : 0.f;
#pragma unroll
            for (int r = 0; r < 4; ++r) {
                float v = acc[i][j][r] + bv;
                if (relu) v = fmaxf(v, 0.f);
                const size_t idx = (size_t)(rbase + r) * N + c;
                if (resid) v += resid[idx];
                if (outb) outb[idx] = f2bs(v);
                else      outf[idx] = v;
            }
        }
    }
}

// ---------------------------------------------------------------------------
// Flash-tile causal attention (f32 internal, bf16 output).
// Block = 256 threads owns 64-query tiles {bx, 31-bx} of one (b,head).
// ---------------------------------------------------------------------------
__global__ __launch_bounds__(256) void attn_k(const float* __restrict__ qkv,
                                              short* __restrict__ att)
{
    __shared__ float Qs[64][65];   // [d][i]
    __shared__ float KP[64][65];   // K [d][s] -> P [s][i]
    __shared__ float Vs[64][65];   // [s][d]
    const int tid  = threadIdx.x;
    const int tx   = tid & 15, ty = tid >> 4;
    const int bh   = blockIdx.y;
    const int b    = bh >> 4, head = bh & 15;
    const int sr   = tid >> 2;
    const int sc   = (tid & 3) * 16;
    const float scale = 0.125f;

#pragma unroll
    for (int pass = 0; pass < 2; ++pass) {
        const int qt = pass == 0 ? blockIdx.x : 31 - blockIdx.x;
        const int t0 = qt * 64;

        {
            const size_t qb = (size_t)(b * SEQ + t0 + sr) * 3072 + head * 64 + sc;
#pragma unroll
            for (int i = 0; i < 16; i += 4) {
                float4 qv = *(const float4*)(qkv + qb + i);
                Qs[sc + i + 0][sr] = qv.x * scale;
                Qs[sc + i + 1][sr] = qv.y * scale;
                Qs[sc + i + 2][sr] = qv.z * scale;
                Qs[sc + i + 3][sr] = qv.w * scale;
            }
        }

        float m[4], l[4], O[4][4];
#pragma unroll
        for (int i = 0; i < 4; ++i) {
            m[i] = -INFINITY; l[i] = 0.f;
#pragma unroll
            for (int j = 0; j < 4; ++j) O[i][j] = 0.f;
        }

        const int ntiles = qt + 1;
        for (int kt = 0; kt < ntiles; ++kt) {
            const int s0 = kt * 64;
            __syncthreads();
            {
                const size_t kb = (size_t)(b * SEQ + s0 + sr) * 3072
                                  + N_EMBD + head * 64 + sc;
#pragma unroll
                for (int i = 0; i < 16; i += 4) {
                    float4 kv = *(const float4*)(qkv + kb + i);
                    KP[sc + i + 0][sr] = kv.x;
                    KP[sc + i + 1][sr] = kv.y;
                    KP[sc + i + 2][sr] = kv.z;
                    KP[sc + i + 3][sr] = kv.w;
                    *(float4*)&Vs[sr][sc + i] = *(const float4*)(qkv + kb + N_EMBD + i);
                }
            }
            __syncthreads();

            float S[4][4] = {{0.f}};
#pragma unroll 8
            for (int kk = 0; kk < 64; ++kk) {
                float4 a4 = *(const float4*)&Qs[kk][ty * 4];
                float4 b4 = *(const float4*)&KP[kk][tx * 4];
                float ar[4] = {a4.x, a4.y, a4.z, a4.w};
                float br[4] = {b4.x, b4.y, b4.z, b4.w};
#pragma unroll
                for (int i = 0; i < 4; ++i)
#pragma unroll
                    for (int j = 0; j < 4; ++j)
                        S[i][j] = fmaf(ar[i], br[j], S[i][j]);
            }
            if (s0 == t0) {
#pragma unroll
                for (int i = 0; i < 4; ++i)
#pragma unroll
                    for (int j = 0; j < 4; ++j)
                        if (tx * 4 + j > ty * 4 + i) S[i][j] = -INFINITY;
            }

#pragma unroll
            for (int i = 0; i < 4; ++i) {
                float rm = fmaxf(fmaxf(S[i][0], S[i][1]), fmaxf(S[i][2], S[i][3]));
#pragma unroll
                for (int off = 8; off; off >>= 1) rm = fmaxf(rm, __shfl_xor(rm, off, 64));
                const float mn    = fmaxf(m[i], rm);
                const float alpha = __expf(m[i] - mn);
                float ps = 0.f;
#pragma unroll
                for (int j = 0; j < 4; ++j) {
                    S[i][j] = __expf(S[i][j] - mn);
                    ps += S[i][j];
                }
#pragma unroll
                for (int off = 8; off; off >>= 1) ps += __shfl_xor(ps, off, 64);
                l[i] = l[i] * alpha + ps;
#pragma unroll
                for (int j = 0; j < 4; ++j) O[i][j] *= alpha;
                m[i] = mn;
            }

            __syncthreads();
#pragma unroll
            for (int i = 0; i < 4; ++i)
#pragma unroll
                for (int j = 0; j < 4; ++j)
                    KP[tx * 4 + j][ty * 4 + i] = S[i][j];
            __syncthreads();

#pragma unroll 8
            for (int kk = 0; kk < 64; ++kk) {
                float4 p4 = *(const float4*)&KP[kk][ty * 4];
                float4 v4 = *(const float4*)&Vs[kk][tx * 4];
                float pr[4] = {p4.x, p4.y, p4.z, p4.w};
                float vr[4] = {v4.x, v4.y, v4.z, v4.w};
#pragma unroll
                for (int i = 0; i < 4; ++i)
#pragma unroll
                    for (int j = 0; j < 4; ++j)
                        O[i][j] = fmaf(pr[i], vr[j], O[i][j]);
            }
        }

#pragma unroll
        for (int i = 0; i < 4; ++i) {
            const float inv = 1.f / l[i];
            short4 o4;
            o4.x = f2bs(O[i][0] * inv); o4.y = f2bs(O[i][1] * inv);
            o4.z = f2bs(O[i][2] * inv); o4.w = f2bs(O[i][3] * inv);
            *(short4*)(att + (size_t)(b * SEQ + t0 + ty * 4 + i) * N_EMBD
                       + head * 64 + tx * 4) = o4;
        }
        __syncthreads();
    }
}

// ---------------------------------------------------------------------------
extern "C" void kernel_launch(void* const* d_in, const int* in_sizes, int n_in,
                              void* d_out, int out_size, void* d_ws, size_t ws_size,
                              hipStream_t stream)
{
    const float* x     = (const float*)d_in[0];
    const float* Wq    = (const float*)d_in[1];
    const float* Wk    = (const float*)d_in[2];
    const float* Wv    = (const float*)d_in[3];
    const float* Wproj = (const float*)d_in[4];
    const float* bproj = (const float*)d_in[5];
    const float* g1    = (const float*)d_in[6];
    const float* b1    = (const float*)d_in[7];
    const float* g2    = (const float*)d_in[8];
    const float* b2    = (const float*)d_in[9];
    const float* Wff1  = (const float*)d_in[10];
    const float* bff1  = (const float*)d_in[11];
    const float* Wff2  = (const float*)d_in[12];
    const float* bff2  = (const float*)d_in[13];
    float* out = (float*)d_out;

    char* ws = (char*)d_ws;
    // workspace (109 MB):
    short* w2t  = (short*)(ws + 0);          // [3072][1024] bf16 (QKV^T)
    short* wpt  = (short*)(ws + 6291456);    // [1024][1024] bf16
    short* wf1t = (short*)(ws + 8388608);    // [4096][1024] bf16
    short* wf2t = (short*)(ws + 16777216);   // [1024][4096] bf16
    short* h    = (short*)(ws + 25165824);   // [4096][1024] bf16 (=h2)
    float* qkv  = (float*)(ws + 33554432);   // [4096][3072] f32 (ff aliases)
    short* att  = (short*)(ws + 83886080);   // [4096][1024] bf16
    float* x2   = (float*)(ws + 92274688);   // [4096][1024] f32
    short* h2   = h;
    short* ff   = (short*)qkv;               // [4096][4096] bf16 (33.6 <= 50.3 MB)

    // --- weight transposes + converts ---
    tr_cvt<<<dim3(2, 32, 16),  256, 0, stream>>>(Wq, w2t,                1024, 64, 65536, 65536);
    tr_cvt<<<dim3(2, 32, 16),  256, 0, stream>>>(Wk, w2t + 1024 * 1024,  1024, 64, 65536, 65536);
    tr_cvt<<<dim3(2, 32, 16),  256, 0, stream>>>(Wv, w2t + 2048 * 1024,  1024, 64, 65536, 65536);
    tr_cvt<<<dim3(32, 32, 1),  256, 0, stream>>>(Wproj, wpt,  1024, 1024, 0, 0);
    tr_cvt<<<dim3(128, 32, 1), 256, 0, stream>>>(Wff1, wf1t,  1024, 4096, 0, 0);
    tr_cvt<<<dim3(32, 128, 1), 256, 0, stream>>>(Wff2, wf2t,  4096, 1024, 0, 0);

    ln_k<<<ROWS, 256, 0, stream>>>(x, g1, b1, h);
    // QKV: [4096,1024] x [1024,3072] -> f32 qkv
    mfma_gemm<<<dim3(3072 / 128, ROWS / 128), 256, 0, stream>>>(
        h, w2t, nullptr, nullptr, qkv, nullptr, ROWS, 3072, N_EMBD, 0);
    attn_k<<<dim3(SEQ / 128, BATCH * N_HEAD), 256, 0, stream>>>(qkv, att);
    // proj + bias + resid(x) -> f32 x2
    mfma_gemm<<<dim3(N_EMBD / 128, ROWS / 128), 256, 0, stream>>>(
        att, wpt, bproj, x, x2, nullptr, ROWS, N_EMBD, N_EMBD, 0);
    ln_k<<<ROWS, 256, 0, stream>>>(x2, g2, b2, h2);
    // FF1 + bias + relu -> bf16 ff
    mfma_gemm<<<dim3(4096 / 128, ROWS / 128), 256, 0, stream>>>(
        h2, wf1t, bff1, nullptr, nullptr, ff, ROWS, 4096, N_EMBD, 1);
    // FF2 + bias + resid(x2) -> f32 out
    mfma_gemm<<<dim3(N_EMBD / 128, ROWS / 128), 256, 0, stream>>>(
        ff, wf2t, bff2, x2, out, nullptr, ROWS, N_EMBD, 4096, 0);
}

// Round 5
// 477.525 us; speedup vs baseline: 8.1545x; 1.6485x over previous
//
#include <hip/hip_runtime.h>
#include <hip/hip_bf16.h>

#define N_EMBD 1024
#define N_HEAD 16
#define HEADSZ 64
#define BATCH  2
#define SEQ    2048
#define ROWS   (BATCH*SEQ)   /* 4096 */

typedef __attribute__((ext_vector_type(8))) short bf16x8;
typedef __attribute__((ext_vector_type(4))) float f32x4;

__device__ __forceinline__ short f2bs(float v){
    union { __hip_bfloat16 b; short s; } u; u.b = __float2bfloat16(v); return u.s;
}
__device__ __forceinline__ void gload16(const short* g, short* l){
    __builtin_amdgcn_global_load_lds(
        (const __attribute__((address_space(1))) unsigned int*)g,
        (__attribute__((address_space(3))) unsigned int*)l, 16, 0, 0);
}

// ---------------------------------------------------------------------------
// Transpose + f32->bf16 convert: out[j][i] = in[i][j]; in is [R][Cc] f32.
// ---------------------------------------------------------------------------
__global__ __launch_bounds__(256) void tr_cvt(const float* __restrict__ in,
                                              short* __restrict__ out,
                                              int R, int Cc,
                                              size_t in_z, size_t out_z)
{
    __shared__ float t[32][33];
    const int tx = threadIdx.x & 31, ty = threadIdx.x >> 5;
    const int j0 = blockIdx.x * 32, i0 = blockIdx.y * 32;
    const float* ip = in + (size_t)blockIdx.z * in_z;
    short* op = out + (size_t)blockIdx.z * out_z;
#pragma unroll
    for (int p = 0; p < 4; ++p)
        t[ty + p * 8][tx] = ip[(size_t)(i0 + ty + p * 8) * Cc + j0 + tx];
    __syncthreads();
#pragma unroll
    for (int p = 0; p < 4; ++p)
        op[(size_t)(j0 + ty + p * 8) * R + i0 + tx] = f2bs(t[tx][ty + p * 8]);
}

// ---------------------------------------------------------------------------
// bf16 transpose of the V slice of qkv: vt[c][token] = qkv[token][2048+c]
// 64x64 tiles, 256 threads.
// ---------------------------------------------------------------------------
__global__ __launch_bounds__(256) void vt_tr(const short* __restrict__ qkv,
                                             short* __restrict__ vt)
{
    __shared__ short t[64][65];
    const int tid = threadIdx.x;
    const int sr = tid >> 2, sc = (tid & 3) * 16;
    const int col0 = blockIdx.x * 64, tok0 = blockIdx.y * 64;
    const short* ip = qkv + (size_t)(tok0 + sr) * 3072 + 2048 + col0 + sc;
    bf16x8 v0 = *(const bf16x8*)ip;
    bf16x8 v1 = *(const bf16x8*)(ip + 8);
#pragma unroll
    for (int i = 0; i < 8; ++i) { t[sr][sc + i] = v0[i]; t[sr][sc + 8 + i] = v1[i]; }
    __syncthreads();
    bf16x8 a, bq;
#pragma unroll
    for (int i = 0; i < 8; ++i) { a[i] = t[sc + i][sr]; bq[i] = t[sc + 8 + i][sr]; }
    short* op = vt + (size_t)(col0 + sr) * 4096 + tok0 + sc;
    *(bf16x8*)op = a;
    *(bf16x8*)(op + 8) = bq;
}

// ---------------------------------------------------------------------------
// LayerNorm: one block per row of 1024, float4 loads, bf16 output
// ---------------------------------------------------------------------------
__global__ __launch_bounds__(256) void ln_k(const float* __restrict__ x,
                                            const float* __restrict__ g,
                                            const float* __restrict__ bta,
                                            short* __restrict__ out)
{
    const int row = blockIdx.x;
    const int tid = threadIdx.x;
    const float* xr = x + (size_t)row * N_EMBD;
    float4 v = *(const float4*)(xr + tid * 4);
    float s  = v.x + v.y + v.z + v.w;
    float s2 = v.x * v.x + v.y * v.y + v.z * v.z + v.w * v.w;
#pragma unroll
    for (int off = 32; off; off >>= 1) {
        s  += __shfl_xor(s,  off, 64);
        s2 += __shfl_xor(s2, off, 64);
    }
    __shared__ float rs[4], rs2[4];
    const int wave = tid >> 6, lane = tid & 63;
    if (lane == 0) { rs[wave] = s; rs2[wave] = s2; }
    __syncthreads();
    s  = rs[0] + rs[1] + rs[2] + rs[3];
    s2 = rs2[0] + rs2[1] + rs2[2] + rs2[3];
    const float mean = s * (1.f / N_EMBD);
    const float var  = s2 * (1.f / N_EMBD) - mean * mean;
    const float rsig = rsqrtf(var + 1e-5f);
    float4 gv = *(const float4*)(g + tid * 4);
    float4 bv = *(const float4*)(bta + tid * 4);
    short4 o;
    o.x = f2bs((v.x - mean) * rsig * gv.x + bv.x);
    o.y = f2bs((v.y - mean) * rsig * gv.y + bv.y);
    o.z = f2bs((v.z - mean) * rsig * gv.z + bv.z);
    o.w = f2bs((v.w - mean) * rsig * gv.w + bv.w);
    *(short4*)(out + (size_t)row * N_EMBD + tid * 4) = o;
}

// ---------------------------------------------------------------------------
// MFMA GEMM (m97 structure): C[M,N] = A[M,K] * Bt[N,K]^T, bf16 in, f32 acc.
// ---------------------------------------------------------------------------
__global__ __launch_bounds__(256) void mfma_gemm(
    const short* __restrict__ A,    // [M][K] bf16
    const short* __restrict__ Bt,   // [N][K] bf16
    const float* __restrict__ bias,
    const float* __restrict__ resid,
    float* __restrict__ outf,
    short* __restrict__ outb,
    int M, int N, int K, int relu)
{
    __shared__ __align__(16) short As[128 * 32];
    __shared__ __align__(16) short Bs[128 * 32];
    const int tid  = threadIdx.x;
    const int lane = tid & 63, w = tid >> 6;
    const int quad = lane >> 4, l16 = lane & 15;
    const int row0 = blockIdx.y * 128, col0 = blockIdx.x * 128;
    const int wm = (w >> 1) * 64, wn = (w & 1) * 64;

    f32x4 acc[4][4];
#pragma unroll
    for (int i = 0; i < 4; ++i)
#pragma unroll
        for (int j = 0; j < 4; ++j)
            acc[i][j] = f32x4{0.f, 0.f, 0.f, 0.f};

    const int c0  = w * 128 + lane;
    const int c1  = c0 + 64;
    const int ar0 = c0 >> 2, ak0 = (c0 & 3) * 8;
    const int ar1 = c1 >> 2, ak1 = (c1 & 3) * 8;
    const short* aG0 = A  + (size_t)(row0 + ar0) * K + ak0;
    const short* aG1 = A  + (size_t)(row0 + ar1) * K + ak1;
    const short* bG0 = Bt + (size_t)(col0 + ar0) * K + ak0;
    const short* bG1 = Bt + (size_t)(col0 + ar1) * K + ak1;
    short* aL0 = As + (size_t)w * 1024;
    short* aL1 = aL0 + 512;
    short* bL0 = Bs + (size_t)w * 1024;
    short* bL1 = bL0 + 512;

    for (int k0 = 0; k0 < K; k0 += 32) {
        __syncthreads();
        gload16(aG0 + k0, aL0);
        gload16(aG1 + k0, aL1);
        gload16(bG0 + k0, bL0);
        gload16(bG1 + k0, bL1);
        asm volatile("s_waitcnt vmcnt(0)" ::: "memory");
        __syncthreads();

        bf16x8 af[4], bfr[4];
#pragma unroll
        for (int i = 0; i < 4; ++i)
            af[i]  = *(const bf16x8*)(As + (wm + i * 16 + l16) * 32 + quad * 8);
#pragma unroll
        for (int j = 0; j < 4; ++j)
            bfr[j] = *(const bf16x8*)(Bs + (wn + j * 16 + l16) * 32 + quad * 8);
#pragma unroll
        for (int i = 0; i < 4; ++i)
#pragma unroll
            for (int j = 0; j < 4; ++j)
                acc[i][j] = __builtin_amdgcn_mfma_f32_16x16x32_bf16(
                    af[i], bfr[j], acc[i][j], 0, 0, 0);
    }

#pragma unroll
    for (int i = 0; i < 4; ++i) {
        const int rbase = row0 + wm + i * 16 + quad * 4;
#pragma unroll
        for (int j = 0; j < 4; ++j) {
            const int c = col0 + wn + j * 16 + l16;
            const float bv = bias ? bias[c] : 0.f;
#pragma unroll
            for (int r = 0; r < 4; ++r) {
                float v = acc[i][j][r] + bv;
                if (relu) v = fmaxf(v, 0.f);
                const size_t idx = (size_t)(rbase + r) * N + c;
                if (resid) v += resid[idx];
                if (outb) outb[idx] = f2bs(v);
                else      outf[idx] = v;
            }
        }
    }
}

// ---------------------------------------------------------------------------
// MFMA flash attention. qkv bf16 [4096][3072]; vt bf16 [1024][4096] (V^T).
// Block = 4 waves, 64-query tile; wave w owns q rows [w*16, w*16+16).
// Q-frags in registers; K [s][d] and V^T [d][s] tiles staged via
// global_load_lds; P round-trips LDS (stride 72 shorts keeps b128 aligned,
// wave-local so lgkmcnt suffices). Processes q-tile pair {bx, 31-bx}.
// ---------------------------------------------------------------------------
__global__ __launch_bounds__(256) void attn_k(const short* __restrict__ qkv,
                                              const short* __restrict__ vt,
                                              short* __restrict__ att)
{
    __shared__ __align__(16) short Ks[64 * 64];   // [s][d]
    __shared__ __align__(16) short Vs[64 * 64];   // [d][s]
    __shared__ __align__(16) short Ps[64 * 72];   // [q][s], stride 72
    const int tid  = threadIdx.x;
    const int lane = tid & 63, w = tid >> 6;
    const int quad = lane >> 4, l16 = lane & 15;
    const int bh = blockIdx.y, b = bh >> 4, head = bh & 15;
    const float scale = 0.125f;

    const int srow = lane >> 3;            // 0..7
    const int scol = (lane & 7) * 8;       // 0,8,..,56 (shorts)
    short* kL0 = Ks + w * 1024; short* kL1 = kL0 + 512;
    short* vL0 = Vs + w * 1024; short* vL1 = vL0 + 512;

#pragma unroll
    for (int pass = 0; pass < 2; ++pass) {
        const int qt = pass == 0 ? blockIdx.x : 31 - blockIdx.x;
        const int t0 = qt * 64;

        // Q fragments (registers): A[m=l16][k=quad*8+j], rows t0+w*16+l16
        const short* qp = qkv + (size_t)(b * SEQ + t0 + w * 16 + l16) * 3072
                          + head * 64 + quad * 8;
        bf16x8 qf0 = *(const bf16x8*)qp;
        bf16x8 qf1 = *(const bf16x8*)(qp + 32);

        float mrow[4], lrow[4];
        f32x4 O[4];
#pragma unroll
        for (int r = 0; r < 4; ++r) { mrow[r] = -INFINITY; lrow[r] = 0.f; }
#pragma unroll
        for (int jn = 0; jn < 4; ++jn) O[jn] = f32x4{0.f, 0.f, 0.f, 0.f};

        const int ntiles = qt + 1;
        for (int kt = 0; kt < ntiles; ++kt) {
            const int s0 = kt * 64;
            __syncthreads();   // prev tile's Ks/Vs reads done
            {
                const short* kg = qkv + (size_t)(b * SEQ + s0 + w * 16 + srow) * 3072
                                  + 1024 + head * 64 + scol;
                gload16(kg, kL0);
                gload16(kg + (size_t)8 * 3072, kL1);
                const short* vg = vt + (size_t)(head * 64 + w * 16 + srow) * 4096
                                  + b * SEQ + s0 + scol;
                gload16(vg, vL0);
                gload16(vg + (size_t)8 * 4096, vL1);
            }
            asm volatile("s_waitcnt vmcnt(0)" ::: "memory");
            __syncthreads();

            // --- S = Q.K^T : 2 MFMAs per 16-col block ---
            f32x4 S[4];
#pragma unroll
            for (int jn = 0; jn < 4; ++jn) {
                S[jn] = f32x4{0.f, 0.f, 0.f, 0.f};
                const short* kp = Ks + (jn * 16 + l16) * 64 + quad * 8;
                bf16x8 b0 = *(const bf16x8*)kp;
                bf16x8 b1 = *(const bf16x8*)(kp + 32);
                S[jn] = __builtin_amdgcn_mfma_f32_16x16x32_bf16(qf0, b0, S[jn], 0, 0, 0);
                S[jn] = __builtin_amdgcn_mfma_f32_16x16x32_bf16(qf1, b1, S[jn], 0, 0, 0);
            }

            // --- softmax in C/D layout: row=quad*4+r, col=jn*16+l16 ---
            float Sv[4][4];
            const int tq = t0 + w * 16 + quad * 4;
#pragma unroll
            for (int jn = 0; jn < 4; ++jn)
#pragma unroll
                for (int r = 0; r < 4; ++r)
                    Sv[jn][r] = S[jn][r] * scale;
            if (s0 == t0) {   // diagonal tile: causal mask
#pragma unroll
                for (int jn = 0; jn < 4; ++jn)
#pragma unroll
                    for (int r = 0; r < 4; ++r)
                        if (s0 + jn * 16 + l16 > tq + r) Sv[jn][r] = -INFINITY;
            }
#pragma unroll
            for (int r = 0; r < 4; ++r) {
                float rm = fmaxf(fmaxf(Sv[0][r], Sv[1][r]), fmaxf(Sv[2][r], Sv[3][r]));
#pragma unroll
                for (int off = 8; off; off >>= 1) rm = fmaxf(rm, __shfl_xor(rm, off, 64));
                const float mn    = fmaxf(mrow[r], rm);
                const float alpha = __expf(mrow[r] - mn);   // 0 on first tile
                float ps = 0.f;
#pragma unroll
                for (int jn = 0; jn < 4; ++jn) {
                    Sv[jn][r] = __expf(Sv[jn][r] - mn);
                    ps += Sv[jn][r];
                }
#pragma unroll
                for (int off = 8; off; off >>= 1) ps += __shfl_xor(ps, off, 64);
                lrow[r] = lrow[r] * alpha + ps;
                mrow[r] = mn;
#pragma unroll
                for (int jn = 0; jn < 4; ++jn) O[jn][r] *= alpha;
            }

            // --- P -> LDS (wave-local rows; no cross-wave barrier needed) ---
#pragma unroll
            for (int jn = 0; jn < 4; ++jn)
#pragma unroll
                for (int r = 0; r < 4; ++r)
                    Ps[(w * 16 + quad * 4 + r) * 72 + jn * 16 + l16] = f2bs(Sv[jn][r]);
            asm volatile("s_waitcnt lgkmcnt(0)" ::: "memory");

            // --- O += P.V ---
            const short* pp = Ps + (w * 16 + l16) * 72 + quad * 8;
            bf16x8 pf0 = *(const bf16x8*)pp;
            bf16x8 pf1 = *(const bf16x8*)(pp + 32);
#pragma unroll
            for (int jn = 0; jn < 4; ++jn) {
                const short* vp = Vs + (jn * 16 + l16) * 64 + quad * 8;
                bf16x8 v0 = *(const bf16x8*)vp;
                bf16x8 v1 = *(const bf16x8*)(vp + 32);
                O[jn] = __builtin_amdgcn_mfma_f32_16x16x32_bf16(pf0, v0, O[jn], 0, 0, 0);
                O[jn] = __builtin_amdgcn_mfma_f32_16x16x32_bf16(pf1, v1, O[jn], 0, 0, 0);
            }
        }

        // --- write O/l ---
#pragma unroll
        for (int r = 0; r < 4; ++r) {
            const float inv = 1.f / lrow[r];
            const size_t rowoff = (size_t)(b * SEQ + t0 + w * 16 + quad * 4 + r) * N_EMBD
                                  + head * 64 + l16;
#pragma unroll
            for (int jn = 0; jn < 4; ++jn)
                att[rowoff + jn * 16] = f2bs(O[jn][r] * inv);
        }
    }
}

// ---------------------------------------------------------------------------
extern "C" void kernel_launch(void* const* d_in, const int* in_sizes, int n_in,
                              void* d_out, int out_size, void* d_ws, size_t ws_size,
                              hipStream_t stream)
{
    const float* x     = (const float*)d_in[0];
    const float* Wq    = (const float*)d_in[1];
    const float* Wk    = (const float*)d_in[2];
    const float* Wv    = (const float*)d_in[3];
    const float* Wproj = (const float*)d_in[4];
    const float* bproj = (const float*)d_in[5];
    const float* g1    = (const float*)d_in[6];
    const float* b1    = (const float*)d_in[7];
    const float* g2    = (const float*)d_in[8];
    const float* b2    = (const float*)d_in[9];
    const float* Wff1  = (const float*)d_in[10];
    const float* bff1  = (const float*)d_in[11];
    const float* Wff2  = (const float*)d_in[12];
    const float* bff2  = (const float*)d_in[13];
    float* out = (float*)d_out;

    char* ws = (char*)d_ws;
    // workspace (92.3 MB):
    short* w2t  = (short*)(ws + 0);          // [3072][1024] bf16 (QKV^T)
    short* wpt  = (short*)(ws + 6291456);    // [1024][1024] bf16
    short* wf1t = (short*)(ws + 8388608);    // [4096][1024] bf16
    short* wf2t = (short*)(ws + 16777216);   // [1024][4096] bf16
    short* h    = (short*)(ws + 25165824);   // [4096][1024] bf16 (=h2)
    short* qkv  = (short*)(ws + 33554432);   // [4096][3072] bf16
    short* vt   = (short*)(ws + 58720256);   // [1024][4096] bf16 (V^T)
    short* att  = (short*)(ws + 67108864);   // [4096][1024] bf16
    float* x2   = (float*)(ws + 75497472);   // [4096][1024] f32
    short* h2   = h;
    short* ff   = qkv;                       // [4096][4096] bf16 aliases qkv+vt
                                             // (both dead after attn; 33.55 MB fits)

    tr_cvt<<<dim3(2, 32, 16),  256, 0, stream>>>(Wq, w2t,                1024, 64, 65536, 65536);
    tr_cvt<<<dim3(2, 32, 16),  256, 0, stream>>>(Wk, w2t + 1024 * 1024,  1024, 64, 65536, 65536);
    tr_cvt<<<dim3(2, 32, 16),  256, 0, stream>>>(Wv, w2t + 2048 * 1024,  1024, 64, 65536, 65536);
    tr_cvt<<<dim3(32, 32, 1),  256, 0, stream>>>(Wproj, wpt,  1024, 1024, 0, 0);
    tr_cvt<<<dim3(128, 32, 1), 256, 0, stream>>>(Wff1, wf1t,  1024, 4096, 0, 0);
    tr_cvt<<<dim3(32, 128, 1), 256, 0, stream>>>(Wff2, wf2t,  4096, 1024, 0, 0);

    ln_k<<<ROWS, 256, 0, stream>>>(x, g1, b1, h);
    // QKV: [4096,1024] x [1024,3072] -> bf16 qkv
    mfma_gemm<<<dim3(3072 / 128, ROWS / 128), 256, 0, stream>>>(
        h, w2t, nullptr, nullptr, nullptr, qkv, ROWS, 3072, N_EMBD, 0);
    vt_tr<<<dim3(16, 64), 256, 0, stream>>>(qkv, vt);
    attn_k<<<dim3(SEQ / 128, BATCH * N_HEAD), 256, 0, stream>>>(qkv, vt, att);
    // proj + bias + resid(x) -> f32 x2
    mfma_gemm<<<dim3(N_EMBD / 128, ROWS / 128), 256, 0, stream>>>(
        att, wpt, bproj, x, x2, nullptr, ROWS, N_EMBD, N_EMBD, 0);
    ln_k<<<ROWS, 256, 0, stream>>>(x2, g2, b2, h2);
    // FF1 + bias + relu -> bf16 ff
    mfma_gemm<<<dim3(4096 / 128, ROWS / 128), 256, 0, stream>>>(
        h2, wf1t, bff1, nullptr, nullptr, ff, ROWS, 4096, N_EMBD, 1);
    // FF2 + bias + resid(x2) -> f32 out
    mfma_gemm<<<dim3(N_EMBD / 128, ROWS / 128), 256, 0, stream>>>(
        ff, wf2t, bff2, x2, out, nullptr, ROWS, N_EMBD, 4096, 0);
}

// Round 6
// 445.257 us; speedup vs baseline: 8.7455x; 1.0725x over previous
//
#include <hip/hip_runtime.h>
#include <hip/hip_bf16.h>

#define N_EMBD 1024
#define N_HEAD 16
#define HEADSZ 64
#define BATCH  2
#define SEQ    2048
#define ROWS   (BATCH*SEQ)   /* 4096 */

typedef __attribute__((ext_vector_type(8))) short bf16x8;
typedef __attribute__((ext_vector_type(4))) float f32x4;

__device__ __forceinline__ short f2bs(float v){
    union { __hip_bfloat16 b; short s; } u; u.b = __float2bfloat16(v); return u.s;
}
__device__ __forceinline__ void gload16(const short* g, short* l){
    __builtin_amdgcn_global_load_lds(
        (const __attribute__((address_space(1))) unsigned int*)g,
        (__attribute__((address_space(3))) unsigned int*)l, 16, 0, 0);
}

// ---------------------------------------------------------------------------
// Transpose + f32->bf16 convert: out[j][i] = in[i][j]; in is [R][Cc] f32.
// ---------------------------------------------------------------------------
__global__ __launch_bounds__(256) void tr_cvt(const float* __restrict__ in,
                                              short* __restrict__ out,
                                              int R, int Cc,
                                              size_t in_z, size_t out_z)
{
    __shared__ float t[32][33];
    const int tx = threadIdx.x & 31, ty = threadIdx.x >> 5;
    const int j0 = blockIdx.x * 32, i0 = blockIdx.y * 32;
    const float* ip = in + (size_t)blockIdx.z * in_z;
    short* op = out + (size_t)blockIdx.z * out_z;
#pragma unroll
    for (int p = 0; p < 4; ++p)
        t[ty + p * 8][tx] = ip[(size_t)(i0 + ty + p * 8) * Cc + j0 + tx];
    __syncthreads();
#pragma unroll
    for (int p = 0; p < 4; ++p)
        op[(size_t)(j0 + ty + p * 8) * R + i0 + tx] = f2bs(t[tx][ty + p * 8]);
}

// Fused Wq/Wk/Wv transpose: z = which*16 + head; per-head [1024][64] -> [64][1024]
__global__ __launch_bounds__(256) void tr3_cvt(const float* __restrict__ Wq,
                                               const float* __restrict__ Wk,
                                               const float* __restrict__ Wv,
                                               short* __restrict__ w2t)
{
    __shared__ float t[32][33];
    const int tx = threadIdx.x & 31, ty = threadIdx.x >> 5;
    const int which = blockIdx.z >> 4, head = blockIdx.z & 15;
    const int j0 = blockIdx.x * 32, i0 = blockIdx.y * 32;
    const float* ip = (which == 0 ? Wq : which == 1 ? Wk : Wv) + (size_t)head * 65536;
    short* op = w2t + (size_t)which * 1048576 + (size_t)head * 65536;
#pragma unroll
    for (int p = 0; p < 4; ++p)
        t[ty + p * 8][tx] = ip[(size_t)(i0 + ty + p * 8) * 64 + j0 + tx];
    __syncthreads();
#pragma unroll
    for (int p = 0; p < 4; ++p)
        op[(size_t)(j0 + ty + p * 8) * 1024 + i0 + tx] = f2bs(t[tx][ty + p * 8]);
}

// ---------------------------------------------------------------------------
// bf16 transpose of the V slice of qkv: vt[c][token] = qkv[token][2048+c]
// ---------------------------------------------------------------------------
__global__ __launch_bounds__(256) void vt_tr(const short* __restrict__ qkv,
                                             short* __restrict__ vt)
{
    __shared__ short t[64][65];
    const int tid = threadIdx.x;
    const int sr = tid >> 2, sc = (tid & 3) * 16;
    const int col0 = blockIdx.x * 64, tok0 = blockIdx.y * 64;
    const short* ip = qkv + (size_t)(tok0 + sr) * 3072 + 2048 + col0 + sc;
    bf16x8 v0 = *(const bf16x8*)ip;
    bf16x8 v1 = *(const bf16x8*)(ip + 8);
#pragma unroll
    for (int i = 0; i < 8; ++i) { t[sr][sc + i] = v0[i]; t[sr][sc + 8 + i] = v1[i]; }
    __syncthreads();
    bf16x8 a, bq;
#pragma unroll
    for (int i = 0; i < 8; ++i) { a[i] = t[sc + i][sr]; bq[i] = t[sc + 8 + i][sr]; }
    short* op = vt + (size_t)(col0 + sr) * 4096 + tok0 + sc;
    *(bf16x8*)op = a;
    *(bf16x8*)(op + 8) = bq;
}

// ---------------------------------------------------------------------------
// LayerNorm: one block per row of 1024, float4 loads, bf16 output
// ---------------------------------------------------------------------------
__global__ __launch_bounds__(256) void ln_k(const float* __restrict__ x,
                                            const float* __restrict__ g,
                                            const float* __restrict__ bta,
                                            short* __restrict__ out)
{
    const int row = blockIdx.x;
    const int tid = threadIdx.x;
    const float* xr = x + (size_t)row * N_EMBD;
    float4 v = *(const float4*)(xr + tid * 4);
    float s  = v.x + v.y + v.z + v.w;
    float s2 = v.x * v.x + v.y * v.y + v.z * v.z + v.w * v.w;
#pragma unroll
    for (int off = 32; off; off >>= 1) {
        s  += __shfl_xor(s,  off, 64);
        s2 += __shfl_xor(s2, off, 64);
    }
    __shared__ float rs[4], rs2[4];
    const int wave = tid >> 6, lane = tid & 63;
    if (lane == 0) { rs[wave] = s; rs2[wave] = s2; }
    __syncthreads();
    s  = rs[0] + rs[1] + rs[2] + rs[3];
    s2 = rs2[0] + rs2[1] + rs2[2] + rs2[3];
    const float mean = s * (1.f / N_EMBD);
    const float var  = s2 * (1.f / N_EMBD) - mean * mean;
    const float rsig = rsqrtf(var + 1e-5f);
    float4 gv = *(const float4*)(g + tid * 4);
    float4 bv = *(const float4*)(bta + tid * 4);
    short4 o;
    o.x = f2bs((v.x - mean) * rsig * gv.x + bv.x);
    o.y = f2bs((v.y - mean) * rsig * gv.y + bv.y);
    o.z = f2bs((v.z - mean) * rsig * gv.z + bv.z);
    o.w = f2bs((v.w - mean) * rsig * gv.w + bv.w);
    *(short4*)(out + (size_t)row * N_EMBD + tid * 4) = o;
}

// ---------------------------------------------------------------------------
// MFMA GEMM (m97 structure): C[M,N] = A[M,K] * Bt[N,K]^T, bf16 in, f32 acc.
// Split-K: kz>0 -> block z handles K range [z*kz, (z+1)*kz); z=0 writes outf,
// z=1 writes outf2 (raw partials, no bias/resid). kz=0 -> full K, outf/outb.
// ---------------------------------------------------------------------------
__global__ __launch_bounds__(256) void mfma_gemm(
    const short* __restrict__ A,    // [M][K] bf16
    const short* __restrict__ Bt,   // [N][K] bf16
    const float* __restrict__ bias,
    const float* __restrict__ resid,
    float* __restrict__ outf,
    float* __restrict__ outf2,
    short* __restrict__ outb,
    int M, int N, int K, int kz, int relu)
{
    __shared__ __align__(16) short As[128 * 32];
    __shared__ __align__(16) short Bs[128 * 32];
    const int tid  = threadIdx.x;
    const int lane = tid & 63, w = tid >> 6;
    const int quad = lane >> 4, l16 = lane & 15;
    const int row0 = blockIdx.y * 128, col0 = blockIdx.x * 128;
    const int wm = (w >> 1) * 64, wn = (w & 1) * 64;
    const int koff = blockIdx.z * kz;
    const int kend = kz ? kz : K;

    f32x4 acc[4][4];
#pragma unroll
    for (int i = 0; i < 4; ++i)
#pragma unroll
        for (int j = 0; j < 4; ++j)
            acc[i][j] = f32x4{0.f, 0.f, 0.f, 0.f};

    const int c0  = w * 128 + lane;
    const int c1  = c0 + 64;
    const int ar0 = c0 >> 2, ak0 = (c0 & 3) * 8;
    const int ar1 = c1 >> 2, ak1 = (c1 & 3) * 8;
    const short* aG0 = A  + (size_t)(row0 + ar0) * K + koff + ak0;
    const short* aG1 = A  + (size_t)(row0 + ar1) * K + koff + ak1;
    const short* bG0 = Bt + (size_t)(col0 + ar0) * K + koff + ak0;
    const short* bG1 = Bt + (size_t)(col0 + ar1) * K + koff + ak1;
    short* aL0 = As + (size_t)w * 1024;
    short* aL1 = aL0 + 512;
    short* bL0 = Bs + (size_t)w * 1024;
    short* bL1 = bL0 + 512;

    for (int k0 = 0; k0 < kend; k0 += 32) {
        __syncthreads();
        gload16(aG0 + k0, aL0);
        gload16(aG1 + k0, aL1);
        gload16(bG0 + k0, bL0);
        gload16(bG1 + k0, bL1);
        asm volatile("s_waitcnt vmcnt(0)" ::: "memory");
        __syncthreads();

        bf16x8 af[4], bfr[4];
#pragma unroll
        for (int i = 0; i < 4; ++i)
            af[i]  = *(const bf16x8*)(As + (wm + i * 16 + l16) * 32 + quad * 8);
#pragma unroll
        for (int j = 0; j < 4; ++j)
            bfr[j] = *(const bf16x8*)(Bs + (wn + j * 16 + l16) * 32 + quad * 8);
#pragma unroll
        for (int i = 0; i < 4; ++i)
#pragma unroll
            for (int j = 0; j < 4; ++j)
                acc[i][j] = __builtin_amdgcn_mfma_f32_16x16x32_bf16(
                    af[i], bfr[j], acc[i][j], 0, 0, 0);
    }

    float* of = blockIdx.z ? outf2 : outf;
#pragma unroll
    for (int i = 0; i < 4; ++i) {
        const int rbase = row0 + wm + i * 16 + quad * 4;
#pragma unroll
        for (int j = 0; j < 4; ++j) {
            const int c = col0 + wn + j * 16 + l16;
            const float bv = bias ? bias[c] : 0.f;
#pragma unroll
            for (int r = 0; r < 4; ++r) {
                float v = acc[i][j][r] + bv;
                if (relu) v = fmaxf(v, 0.f);
                const size_t idx = (size_t)(rbase + r) * N + c;
                if (resid) v += resid[idx];
                if (outb) outb[idx] = f2bs(v);
                else      of[idx] = v;
            }
        }
    }
}

// ---------------------------------------------------------------------------
// FF2 finalize: out = p0 + out + bias + x2   (all f32, N=1024 bias period)
// ---------------------------------------------------------------------------
__global__ __launch_bounds__(256) void ff2_fin(const float* __restrict__ p0,
                                               const float* __restrict__ bias,
                                               const float* __restrict__ x2,
                                               float* __restrict__ out)
{
    const size_t i = ((size_t)blockIdx.x * 256 + threadIdx.x) * 4;
    float4 a = *(const float4*)(p0 + i);
    float4 b = *(const float4*)(out + i);
    float4 r = *(const float4*)(x2 + i);
    float4 bb = *(const float4*)(bias + (i & 1023));
    float4 o;
    o.x = a.x + b.x + r.x + bb.x;
    o.y = a.y + b.y + r.y + bb.y;
    o.z = a.z + b.z + r.z + bb.z;
    o.w = a.w + b.w + r.w + bb.w;
    *(float4*)(out + i) = o;
}

// ---------------------------------------------------------------------------
// MFMA flash attention (unchanged from R5).
// ---------------------------------------------------------------------------
__global__ __launch_bounds__(256) void attn_k(const short* __restrict__ qkv,
                                              const short* __restrict__ vt,
                                              short* __restrict__ att)
{
    __shared__ __align__(16) short Ks[64 * 64];   // [s][d]
    __shared__ __align__(16) short Vs[64 * 64];   // [d][s]
    __shared__ __align__(16) short Ps[64 * 72];   // [q][s], stride 72
    const int tid  = threadIdx.x;
    const int lane = tid & 63, w = tid >> 6;
    const int quad = lane >> 4, l16 = lane & 15;
    const int bh = blockIdx.y, b = bh >> 4, head = bh & 15;
    const float scale = 0.125f;

    const int srow = lane >> 3;
    const int scol = (lane & 7) * 8;
    short* kL0 = Ks + w * 1024; short* kL1 = kL0 + 512;
    short* vL0 = Vs + w * 1024; short* vL1 = vL0 + 512;

#pragma unroll
    for (int pass = 0; pass < 2; ++pass) {
        const int qt = pass == 0 ? blockIdx.x : 31 - blockIdx.x;
        const int t0 = qt * 64;

        const short* qp = qkv + (size_t)(b * SEQ + t0 + w * 16 + l16) * 3072
                          + head * 64 + quad * 8;
        bf16x8 qf0 = *(const bf16x8*)qp;
        bf16x8 qf1 = *(const bf16x8*)(qp + 32);

        float mrow[4], lrow[4];
        f32x4 O[4];
#pragma unroll
        for (int r = 0; r < 4; ++r) { mrow[r] = -INFINITY; lrow[r] = 0.f; }
#pragma unroll
        for (int jn = 0; jn < 4; ++jn) O[jn] = f32x4{0.f, 0.f, 0.f, 0.f};

        const int ntiles = qt + 1;
        for (int kt = 0; kt < ntiles; ++kt) {
            const int s0 = kt * 64;
            __syncthreads();
            {
                const short* kg = qkv + (size_t)(b * SEQ + s0 + w * 16 + srow) * 3072
                                  + 1024 + head * 64 + scol;
                gload16(kg, kL0);
                gload16(kg + (size_t)8 * 3072, kL1);
                const short* vg = vt + (size_t)(head * 64 + w * 16 + srow) * 4096
                                  + b * SEQ + s0 + scol;
                gload16(vg, vL0);
                gload16(vg + (size_t)8 * 4096, vL1);
            }
            asm volatile("s_waitcnt vmcnt(0)" ::: "memory");
            __syncthreads();

            f32x4 S[4];
#pragma unroll
            for (int jn = 0; jn < 4; ++jn) {
                S[jn] = f32x4{0.f, 0.f, 0.f, 0.f};
                const short* kp = Ks + (jn * 16 + l16) * 64 + quad * 8;
                bf16x8 b0 = *(const bf16x8*)kp;
                bf16x8 b1 = *(const bf16x8*)(kp + 32);
                S[jn] = __builtin_amdgcn_mfma_f32_16x16x32_bf16(qf0, b0, S[jn], 0, 0, 0);
                S[jn] = __builtin_amdgcn_mfma_f32_16x16x32_bf16(qf1, b1, S[jn], 0, 0, 0);
            }

            float Sv[4][4];
            const int tq = t0 + w * 16 + quad * 4;
#pragma unroll
            for (int jn = 0; jn < 4; ++jn)
#pragma unroll
                for (int r = 0; r < 4; ++r)
                    Sv[jn][r] = S[jn][r] * scale;
            if (s0 == t0) {
#pragma unroll
                for (int jn = 0; jn < 4; ++jn)
#pragma unroll
                    for (int r = 0; r < 4; ++r)
                        if (s0 + jn * 16 + l16 > tq + r) Sv[jn][r] = -INFINITY;
            }
#pragma unroll
            for (int r = 0; r < 4; ++r) {
                float rm = fmaxf(fmaxf(Sv[0][r], Sv[1][r]), fmaxf(Sv[2][r], Sv[3][r]));
#pragma unroll
                for (int off = 8; off; off >>= 1) rm = fmaxf(rm, __shfl_xor(rm, off, 64));
                const float mn    = fmaxf(mrow[r], rm);
                const float alpha = __expf(mrow[r] - mn);
                float ps = 0.f;
#pragma unroll
                for (int jn = 0; jn < 4; ++jn) {
                    Sv[jn][r] = __expf(Sv[jn][r] - mn);
                    ps += Sv[jn][r];
                }
#pragma unroll
                for (int off = 8; off; off >>= 1) ps += __shfl_xor(ps, off, 64);
                lrow[r] = lrow[r] * alpha + ps;
                mrow[r] = mn;
#pragma unroll
                for (int jn = 0; jn < 4; ++jn) O[jn][r] *= alpha;
            }

#pragma unroll
            for (int jn = 0; jn < 4; ++jn)
#pragma unroll
                for (int r = 0; r < 4; ++r)
                    Ps[(w * 16 + quad * 4 + r) * 72 + jn * 16 + l16] = f2bs(Sv[jn][r]);
            asm volatile("s_waitcnt lgkmcnt(0)" ::: "memory");

            const short* pp = Ps + (w * 16 + l16) * 72 + quad * 8;
            bf16x8 pf0 = *(const bf16x8*)pp;
            bf16x8 pf1 = *(const bf16x8*)(pp + 32);
#pragma unroll
            for (int jn = 0; jn < 4; ++jn) {
                const short* vp = Vs + (jn * 16 + l16) * 64 + quad * 8;
                bf16x8 v0 = *(const bf16x8*)vp;
                bf16x8 v1 = *(const bf16x8*)(vp + 32);
                O[jn] = __builtin_amdgcn_mfma_f32_16x16x32_bf16(pf0, v0, O[jn], 0, 0, 0);
                O[jn] = __builtin_amdgcn_mfma_f32_16x16x32_bf16(pf1, v1, O[jn], 0, 0, 0);
            }
        }

#pragma unroll
        for (int r = 0; r < 4; ++r) {
            const float inv = 1.f / lrow[r];
            const size_t rowoff = (size_t)(b * SEQ + t0 + w * 16 + quad * 4 + r) * N_EMBD
                                  + head * 64 + l16;
#pragma unroll
            for (int jn = 0; jn < 4; ++jn)
                att[rowoff + jn * 16] = f2bs(O[jn][r] * inv);
        }
    }
}

// ---------------------------------------------------------------------------
extern "C" void kernel_launch(void* const* d_in, const int* in_sizes, int n_in,
                              void* d_out, int out_size, void* d_ws, size_t ws_size,
                              hipStream_t stream)
{
    const float* x     = (const float*)d_in[0];
    const float* Wq    = (const float*)d_in[1];
    const float* Wk    = (const float*)d_in[2];
    const float* Wv    = (const float*)d_in[3];
    const float* Wproj = (const float*)d_in[4];
    const float* bproj = (const float*)d_in[5];
    const float* g1    = (const float*)d_in[6];
    const float* b1    = (const float*)d_in[7];
    const float* g2    = (const float*)d_in[8];
    const float* b2    = (const float*)d_in[9];
    const float* Wff1  = (const float*)d_in[10];
    const float* bff1  = (const float*)d_in[11];
    const float* Wff2  = (const float*)d_in[12];
    const float* bff2  = (const float*)d_in[13];
    float* out = (float*)d_out;

    char* ws = (char*)d_ws;
    // workspace (92.3 MB):
    short* w2t  = (short*)(ws + 0);          // [3072][1024] bf16 (dead after QKV)
    short* wpt  = (short*)(ws + 6291456);    // [1024][1024] (dead after proj)
    short* wf1t = (short*)(ws + 8388608);    // [4096][1024] (dead after FF1)
    short* wf2t = (short*)(ws + 16777216);   // [1024][4096]
    short* h    = (short*)(ws + 25165824);   // [4096][1024] (=h2)
    short* qkv  = (short*)(ws + 33554432);   // [4096][3072]
    short* vt   = (short*)(ws + 58720256);   // [1024][4096] (V^T)
    short* att  = (short*)(ws + 67108864);   // [4096][1024]
    float* x2   = (float*)(ws + 75497472);   // [4096][1024] f32
    short* h2   = h;
    short* ff   = qkv;                       // [4096][4096] aliases qkv+vt (dead)
    float* p0   = (float*)(ws + 0);          // [4096][1024] f32 FF2 partial,
                                             // aliases w2t+wpt+wf1t (all dead by FF2)

    tr3_cvt<<<dim3(2, 32, 48),  256, 0, stream>>>(Wq, Wk, Wv, w2t);
    tr_cvt<<<dim3(32, 32, 1),  256, 0, stream>>>(Wproj, wpt,  1024, 1024, 0, 0);
    tr_cvt<<<dim3(128, 32, 1), 256, 0, stream>>>(Wff1, wf1t,  1024, 4096, 0, 0);
    tr_cvt<<<dim3(32, 128, 1), 256, 0, stream>>>(Wff2, wf2t,  4096, 1024, 0, 0);

    ln_k<<<ROWS, 256, 0, stream>>>(x, g1, b1, h);
    // QKV: [4096,1024] x [1024,3072] -> bf16 qkv
    mfma_gemm<<<dim3(3072 / 128, ROWS / 128), 256, 0, stream>>>(
        h, w2t, nullptr, nullptr, nullptr, nullptr, qkv, ROWS, 3072, N_EMBD, 0, 0);
    vt_tr<<<dim3(16, 64), 256, 0, stream>>>(qkv, vt);
    attn_k<<<dim3(SEQ / 128, BATCH * N_HEAD), 256, 0, stream>>>(qkv, vt, att);
    // proj + bias + resid(x) -> f32 x2
    mfma_gemm<<<dim3(N_EMBD / 128, ROWS / 128), 256, 0, stream>>>(
        att, wpt, bproj, x, x2, nullptr, nullptr, ROWS, N_EMBD, N_EMBD, 0, 0);
    ln_k<<<ROWS, 256, 0, stream>>>(x2, g2, b2, h2);
    // FF1 + bias + relu -> bf16 ff
    mfma_gemm<<<dim3(4096 / 128, ROWS / 128), 256, 0, stream>>>(
        h2, wf1t, bff1, nullptr, nullptr, nullptr, ff, ROWS, 4096, N_EMBD, 0, 1);
    // FF2 split-K=2: z=0 -> p0 (K 0..2048), z=1 -> out (K 2048..4096); raw f32
    mfma_gemm<<<dim3(N_EMBD / 128, ROWS / 128, 2), 256, 0, stream>>>(
        ff, wf2t, nullptr, nullptr, p0, out, nullptr, ROWS, N_EMBD, 4096, 2048, 0);
    // out = p0 + out + bias + x2
    ff2_fin<<<ROWS * N_EMBD / 1024, 256, 0, stream>>>(p0, bff2, x2, out);
}